// Round 2
// baseline (155.833 us; speedup 1.0000x reference)
//
#include <hip/hip_runtime.h>

#define IMG   512
#define NIMG  48
#define RB    64            // output rows per block (512/8 row-strips)
#define C1v   1.0e-4f       // 0.01^2
#define C2v   9.0e-4f       // 0.03^2

// Gaussian window, fp64 exp then rounded to f32 — verified absmax 0.0 vs numpy.
__device__ __forceinline__ void make_window(float* w) {
    double v[11];
    double s = 0.0;
    #pragma unroll
    for (int i = 0; i < 11; ++i) {
        float d   = (float)i - 5.0f;
        float arg = -(d * d) / 4.5f;      // 2*sigma^2 = 4.5
        v[i] = exp((double)arg);
        s += v[i];
    }
    #pragma unroll
    for (int i = 0; i < 11; ++i) w[i] = (float)(v[i] / s);
}

// One thread owns one image column x, producing RB output rows starting at y0.
// H-pass: 11-tap window from global (L1-served, imm offsets), masked weights wm
// handle x zero-padding. V-pass: scatter into an 11-slot ring of pending
// accumulators (static indices via 11-unrolled row loop). GUARD path exec-masks
// the loads whose address could leave the buffer (only 4 blocks need it).
template<bool GUARD>
__device__ float ssim_column(const float* __restrict__ Pb,
                             const float* __restrict__ Tb,
                             int y0, int x,
                             const float* __restrict__ w,
                             const float* __restrict__ wm) {
    float m1[11], m2[11], e1[11], e2[11], e3[11];
    #pragma unroll
    for (int s = 0; s < 11; ++s) { m1[s]=0.f; m2[s]=0.f; e1[s]=0.f; e2[s]=0.f; e3[s]=0.f; }

    const float* Pr = Pb + (long)(y0 - 5) * IMG + (x - 5);
    const float* Tr = Tb + (long)(y0 - 5) * IMG + (x - 5);
    float acc = 0.f;

    // 77 rows = 7 groups of 11 (ring phase static per unrolled g)
    #pragma unroll 1
    for (int grp = 0; grp < 7; ++grp) {
        #pragma unroll
        for (int g = 0; g < 11; ++g) {
            const int i = grp * 11 + g;          // local row index, r = y0-5+i
            const int r = y0 - 5 + i;
            if (r >= 0 && r < IMG) {
                // ---- horizontal 11-tap stats for (r, x) ----
                float h1 = 0.f, h2 = 0.f, hx = 0.f, hy = 0.f, hz = 0.f;
                #pragma unroll
                for (int j = 0; j < 11; ++j) {
                    if (!GUARD || wm[j] != 0.0f) {
                        const float p = Pr[j];
                        const float t = Tr[j];
                        h1 += wm[j] * p;
                        h2 += wm[j] * t;
                        hx += wm[j] * (p * p);
                        hy += wm[j] * (t * t);
                        hz += wm[j] * (p * t);
                    }
                }
                // ---- vertical scatter: h-row r feeds outputs y = r-5..r+5 ----
                // k-th target: local out l = i-10+k, slot (g+1+k)%11, weight w[10-k]
                #pragma unroll
                for (int k = 0; k < 11; ++k) {
                    const int  s  = (g + 1 + k) % 11;
                    const float wv = w[10 - k];
                    m1[s] += wv * h1;
                    m2[s] += wv * h2;
                    e1[s] += wv * hx;
                    e2[s] += wv * hy;
                    e3[s] += wv * hz;
                }
            }
            // ---- retire output l = i-10 (slot (g+1)%11), then recycle slot ----
            {
                const int l = i - 10;
                const int s = (g + 1) % 11;
                if (l >= 0 && l < RB) {
                    const float mu1 = m1[s], mu2 = m2[s];
                    const float mu1sq = mu1 * mu1;
                    const float mu2sq = mu2 * mu2;
                    const float mu12  = mu1 * mu2;
                    const float s1  = e1[s] - mu1sq;
                    const float s2  = e2[s] - mu2sq;
                    const float s12 = e3[s] - mu12;
                    const float num = (2.0f * mu12 + C1v) * (2.0f * s12 + C2v);
                    const float den = (mu1sq + mu2sq + C1v) * (s1 + s2 + C2v);
                    acc += num * __builtin_amdgcn_rcpf(den);
                }
                m1[s] = 0.f; m2[s] = 0.f; e1[s] = 0.f; e2[s] = 0.f; e3[s] = 0.f;
            }
            Pr += IMG;
            Tr += IMG;
        }
    }
    return acc;
}

__global__ __launch_bounds__(256) void ssim_kernel(
        const float* __restrict__ pred,
        const float* __restrict__ targ,
        float* __restrict__ partial) {
    const int n  = blockIdx.z;
    const int y0 = blockIdx.y * RB;
    const int x  = blockIdx.x * 256 + threadIdx.x;

    float w[11], wm[11];
    make_window(w);
    #pragma unroll
    for (int j = 0; j < 11; ++j) {
        const int c = x + j - 5;
        wm[j] = (c >= 0 && c < IMG) ? w[j] : 0.0f;
    }

    const float* Pb = pred + (size_t)n * IMG * IMG;
    const float* Tb = targ + (size_t)n * IMG * IMG;

    // only these blocks can form addresses outside [0, NIMG*IMG*IMG)
    const bool edge = (n == 0 && blockIdx.y == 0) ||
                      (n == NIMG - 1 && blockIdx.y == gridDim.y - 1);

    float acc = edge ? ssim_column<true >(Pb, Tb, y0, x, w, wm)
                     : ssim_column<false>(Pb, Tb, y0, x, w, wm);

    // ---- block reduction ----
    #pragma unroll
    for (int off = 32; off > 0; off >>= 1)
        acc += __shfl_down(acc, off, 64);
    __shared__ float wavesum[4];
    const int wv = threadIdx.x >> 6;
    if ((threadIdx.x & 63) == 0) wavesum[wv] = acc;
    __syncthreads();
    if (threadIdx.x == 0) {
        const int bid = (blockIdx.z * gridDim.y + blockIdx.y) * gridDim.x + blockIdx.x;
        partial[bid] = wavesum[0] + wavesum[1] + wavesum[2] + wavesum[3];
    }
}

__global__ __launch_bounds__(256) void ssim_reduce_kernel(
        const float* __restrict__ partial,
        float* __restrict__ out,
        int nblk, double inv_n) {
    __shared__ double wsum[4];
    double s = 0.0;
    for (int i = threadIdx.x; i < nblk; i += 256)
        s += (double)partial[i];
    #pragma unroll
    for (int off = 32; off > 0; off >>= 1)
        s += __shfl_down(s, off, 64);
    const int wv = threadIdx.x >> 6;
    if ((threadIdx.x & 63) == 0) wsum[wv] = s;
    __syncthreads();
    if (threadIdx.x == 0) {
        const double tot = wsum[0] + wsum[1] + wsum[2] + wsum[3];
        out[0] = (float)(tot * inv_n);
    }
}

extern "C" void kernel_launch(void* const* d_in, const int* in_sizes, int n_in,
                              void* d_out, int out_size, void* d_ws, size_t ws_size,
                              hipStream_t stream) {
    const float* pred = (const float*)d_in[0];
    const float* targ = (const float*)d_in[1];
    float* out     = (float*)d_out;
    float* partial = (float*)d_ws;   // 2*8*48 = 768 floats, all written

    dim3 grid(2, IMG / RB, NIMG);    // 2 col-stripes x 8 row-strips x 48 images
    ssim_kernel<<<grid, 256, 0, stream>>>(pred, targ, partial);

    const int nblk = 2 * (IMG / RB) * NIMG;
    const double inv_n = 1.0 / ((double)NIMG * IMG * IMG);
    ssim_reduce_kernel<<<1, 256, 0, stream>>>(partial, out, nblk, inv_n);
}

// Round 3
// 112.799 us; speedup vs baseline: 1.3815x; 1.3815x over previous
//
#include <hip/hip_runtime.h>
#include <math.h>

#define IMG   512
#define NIMG  48
#define RB    32            // output rows per block
#define TX    256           // output columns per block
#define HW    266           // staged cols = TX + 10
#define C1v   1.0e-4f       // 0.01^2
#define C2v   9.0e-4f       // 0.03^2

struct Win { float w[11]; };

// One thread owns one image column; V-pass lives in an 11-slot register ring
// (validated in R2: scatter slot (g+1+k)%11 weight w[10-k], retire (g+1)%11).
// H-pass reads come from an 11-row LDS stage of the raw inputs (R1's
// latency-robust feeding), zero-filled outside the image = reference's
// zero-padding. Window is host-computed, passed by value (SGPRs).
__global__ __launch_bounds__(256) void ssim_kernel(
        const float* __restrict__ pred,
        const float* __restrict__ targ,
        float* __restrict__ partial, Win win) {
    __shared__ float sp[11][HW];
    __shared__ float st[11][HW];
    __shared__ float wavesum[4];

    const int tid = threadIdx.x;
    const int n   = blockIdx.z;
    const int y0  = blockIdx.y * RB;
    const int x0  = blockIdx.x * TX;

    const float* __restrict__ P = pred + (size_t)n * IMG * IMG;
    const float* __restrict__ T = targ + (size_t)n * IMG * IMG;

    float m1[11], m2[11], e1[11], e2[11], e3[11];
    #pragma unroll
    for (int s = 0; s < 11; ++s) { m1[s]=0.f; m2[s]=0.f; e1[s]=0.f; e2[s]=0.f; e3[s]=0.f; }

    float acc = 0.f;

    #pragma unroll 1
    for (int grp = 0; grp < 4; ++grp) {
        // ---- stage 11 input rows [rbase, rbase+10] x [x0-5, x0+260] ----
        const int rbase = y0 - 5 + grp * 11;
        __syncthreads();                      // drain prior group's reads
        for (int idx = tid; idx < 11 * HW; idx += 256) {
            const int rr = idx / HW;
            const int cc = idx - rr * HW;
            const int gy = rbase + rr;
            const int gx = x0 - 5 + cc;
            float p = 0.f, t = 0.f;
            if (gy >= 0 && gy < IMG && gx >= 0 && gx < IMG) {
                const int g = gy * IMG + gx;
                p = P[g]; t = T[g];
            }
            sp[rr][cc] = p;
            st[rr][cc] = t;
        }
        __syncthreads();

        #pragma unroll
        for (int g = 0; g < 11; ++g) {
            const int i = grp * 11 + g;       // row-iter index, r = y0-5+i
            const int r = y0 - 5 + i;         // block-uniform -> scalar branch
            if (r >= 0 && r < IMG) {
                // ---- horizontal 11-tap stats from LDS (stride-1, conflict-free) ----
                float h1 = 0.f, h2 = 0.f, hx = 0.f, hy = 0.f, hz = 0.f;
                #pragma unroll
                for (int j = 0; j < 11; ++j) {
                    const float wj = win.w[j];
                    const float p  = sp[g][tid + j];
                    const float t  = st[g][tid + j];
                    h1 += wj * p;
                    h2 += wj * t;
                    hx += wj * (p * p);
                    hy += wj * (t * t);
                    hz += wj * (p * t);
                }
                // ---- vertical scatter into the register ring ----
                #pragma unroll
                for (int k = 0; k < 11; ++k) {
                    const int   s  = (g + 1 + k) % 11;
                    const float wv = win.w[10 - k];
                    m1[s] += wv * h1;
                    m2[s] += wv * h2;
                    e1[s] += wv * hx;
                    e2[s] += wv * hy;
                    e3[s] += wv * hz;
                }
            }
            // ---- retire output l = i-10 (slot (g+1)%11), recycle slot ----
            {
                const int l = i - 10;
                const int s = (g + 1) % 11;
                if (l >= 0 && l < RB) {
                    const float mu1 = m1[s], mu2 = m2[s];
                    const float mu1sq = mu1 * mu1;
                    const float mu2sq = mu2 * mu2;
                    const float mu12  = mu1 * mu2;
                    const float s1  = e1[s] - mu1sq;
                    const float s2  = e2[s] - mu2sq;
                    const float s12 = e3[s] - mu12;
                    const float num = (2.0f * mu12 + C1v) * (2.0f * s12 + C2v);
                    const float den = (mu1sq + mu2sq + C1v) * (s1 + s2 + C2v);
                    acc += num * __builtin_amdgcn_rcpf(den);
                }
                m1[s] = 0.f; m2[s] = 0.f; e1[s] = 0.f; e2[s] = 0.f; e3[s] = 0.f;
            }
        }
    }

    // ---- block reduction ----
    #pragma unroll
    for (int off = 32; off > 0; off >>= 1)
        acc += __shfl_down(acc, off, 64);
    const int wv = tid >> 6;
    if ((tid & 63) == 0) wavesum[wv] = acc;
    __syncthreads();
    if (tid == 0) {
        const int bid = (blockIdx.z * gridDim.y + blockIdx.y) * gridDim.x + blockIdx.x;
        partial[bid] = wavesum[0] + wavesum[1] + wavesum[2] + wavesum[3];
    }
}

__global__ __launch_bounds__(256) void ssim_reduce_kernel(
        const float* __restrict__ partial,
        float* __restrict__ out,
        int nblk, double inv_n) {
    __shared__ double wsum[4];
    double s = 0.0;
    for (int i = threadIdx.x; i < nblk; i += 256)
        s += (double)partial[i];
    #pragma unroll
    for (int off = 32; off > 0; off >>= 1)
        s += __shfl_down(s, off, 64);
    const int wv = threadIdx.x >> 6;
    if ((threadIdx.x & 63) == 0) wsum[wv] = s;
    __syncthreads();
    if (threadIdx.x == 0) {
        const double tot = wsum[0] + wsum[1] + wsum[2] + wsum[3];
        out[0] = (float)(tot * inv_n);
    }
}

extern "C" void kernel_launch(void* const* d_in, const int* in_sizes, int n_in,
                              void* d_out, int out_size, void* d_ws, size_t ws_size,
                              hipStream_t stream) {
    const float* pred = (const float*)d_in[0];
    const float* targ = (const float*)d_in[1];
    float* out     = (float*)d_out;
    float* partial = (float*)d_ws;   // 2*16*48 = 1536 floats, all written

    Win win;
    {
        double v[11], s = 0.0;
        for (int i = 0; i < 11; ++i) {
            float d   = (float)i - 5.0f;
            float arg = -(d * d) / 4.5f;      // 2*sigma^2 = 4.5
            v[i] = exp((double)arg);
            s += v[i];
        }
        for (int i = 0; i < 11; ++i) win.w[i] = (float)(v[i] / s);
    }

    dim3 grid(IMG / TX, IMG / RB, NIMG);      // (2, 16, 48) = 1536 blocks
    ssim_kernel<<<grid, 256, 0, stream>>>(pred, targ, partial, win);

    const int nblk = (IMG / TX) * (IMG / RB) * NIMG;
    const double inv_n = 1.0 / ((double)NIMG * IMG * IMG);
    ssim_reduce_kernel<<<1, 256, 0, stream>>>(partial, out, nblk, inv_n);
}